// Round 3
// baseline (610.261 us; speedup 1.0000x reference)
//
#include <hip/hip_runtime.h>

// UpsamplingNearestSingle: N=262144 coarse voxels, C=64 ch, SCALE=2 -> 8 children.
// d_out (float32, concatenated): fine_data [N*8,64] then fine_ijk [N*8,3] as floats.
#define N_COARSE    262144
#define CHANNELS    64
#define DATA_F4     (N_COARSE * 8 * 16)   // 33554432 output float4s (fine_data)
#define DATA_BLOCKS 2048                  // persistent: each owns 16384 f4 = 256 KB
#define DATA_PER_T  64                    // f4 per thread (64 * 256 = 16384)
#define IJK_F4      ((N_COARSE * 8 * 3) / 4)  // 1572864 float4s of fine_ijk
#define IJK_BLOCKS  256                   // each owns 6144 f4 = 96 KB
#define IJK_PER_T   24                    // 24 * 256 = 6144

typedef float nfloat4 __attribute__((ext_vector_type(4)));

// FILL-CLONE SHAPE. R0/R1/R2 (one store per thread, ~150k 4KB blocks) all ran
// the kernel portion at ~2.6 TB/s regardless of NT-vs-cached and address
// pattern. The harness fillBuffer — few blocks, long contiguous per-block runs,
// grid-stride — hits 6.25 TB/s on the same buffer. This kernel clones that
// shape: 2048 blocks, each streaming a contiguous 256 KB chunk (1 KB per wave
// per store, sequential walk), plain stores so L2 write-combines long runs.
// Reads: per iteration k the block's 256 threads read 32 distinct input f4s,
// each by 8 lanes simultaneously -> L1 broadcast; HBM read stays 64 MB total.
__global__ void __launch_bounds__(256)
upsample_fused_kernel(const nfloat4* __restrict__ in, const int* __restrict__ ijk,
                      nfloat4* __restrict__ out_data, nfloat4* __restrict__ out_ijk) {
    const int b   = blockIdx.x;
    const int tid = threadIdx.x;
    if (b < DATA_BLOCKS) {
        // Block b owns output f4 range [b*16384, (b+1)*16384).
        // j = b*16384 + k*256 + tid ; src = parent*16 + c4, with
        // j>>7 = b*128 + k*2 + (tid>>7), j&15 = tid&15  =>
        // src = b*2048 + k*32 + ((tid>>7)<<4) + (tid&15)
        const size_t jbase = (size_t)b * 16384 + tid;
        const size_t sbase = (size_t)b * 2048 + ((tid >> 7) << 4) + (tid & 15);
#pragma unroll 8
        for (int k = 0; k < DATA_PER_T; ++k)
            out_data[jbase + (size_t)k * 256] = in[sbase + (size_t)k * 32];
    } else {
        // fine_ijk as packed float4: f4 index t covers elements e = 4t..4t+3.
        const int bi = b - DATA_BLOCKS;
        const int tbase = bi * 6144 + tid;
#pragma unroll 4
        for (int k = 0; k < IJK_PER_T; ++k) {
            const int t = tbase + k * 256;
            nfloat4 v;
#pragma unroll
            for (int m = 0; m < 4; ++m) {
                const int e = 4 * t + m;
                const int r = e / 3;           // fine row (magic-mul)
                const int d = e - r * 3;       // dim 0..2
                const int n = r >> 3;          // parent voxel
                const int o = r & 7;           // child index
                const int off = (o >> (2 - d)) & 1;  // meshgrid ij-order bit
                v[m] = (float)(ijk[n * 3 + d] * 2 + off);
            }
            out_ijk[t] = v;
        }
    }
}

extern "C" void kernel_launch(void* const* d_in, const int* in_sizes, int n_in,
                              void* d_out, int out_size, void* d_ws, size_t ws_size,
                              hipStream_t stream) {
    const nfloat4* coarse_data = (const nfloat4*)d_in[0];
    const int*     coarse_ijk  = (const int*)d_in[1];

    float*   out      = (float*)d_out;
    nfloat4* out_data = (nfloat4*)out;
    nfloat4* out_ijk  = (nfloat4*)(out + (size_t)N_COARSE * 8 * CHANNELS);

    upsample_fused_kernel<<<DATA_BLOCKS + IJK_BLOCKS, 256, 0, stream>>>(
        coarse_data, coarse_ijk, out_data, out_ijk);
}

// Round 4
// 597.656 us; speedup vs baseline: 1.0211x; 1.0211x over previous
//
#include <hip/hip_runtime.h>

// UpsamplingNearestSingle: N=262144 coarse voxels, C=64 ch, SCALE=2 -> 8 children.
// d_out (float32, concatenated): fine_data [N*8,64] then fine_ijk [N*8,3] as floats.
#define N_COARSE 262144
#define CHANNELS 64
#define DATA_F4     (N_COARSE * 8 * 16)   // 33554432 output float4s (fine_data)
#define DATA_BLOCKS 131072                // DATA_F4 / 256
#define IJK_ELEMS   (N_COARSE * 8 * 3)    // 6291456
#define IJK_BLOCKS  24576                 // IJK_ELEMS / 256

typedef float nfloat4 __attribute__((ext_vector_type(4)));

// FINAL (best measured: 597.3 us). Output-driven replication, NT stores.
// Roofline decomposition (R0-R3 evidence): timed iter = harness poison-fill
// (357 us, 2.248 GB @ 6.25 TB/s, immovable) + reset()'s dozens of tiny
// memset/restore dispatches (~140 us, immovable) + this kernel (~100 us).
// Kernel floor = 536 MiB mandated output / 6.3 TB/s achievable ~= 90-100 us.
// Four structurally opposite kernels (input/output-driven, NT/cached,
// one-shot/persistent) all landed 597-610 us => every >=256B-coalesced write
// stream is at the HBM write ceiling; remaining in-kernel headroom <~1%.
__global__ void __launch_bounds__(256)
upsample_fused_kernel(const nfloat4* __restrict__ in, const int* __restrict__ ijk,
                      nfloat4* __restrict__ out_data, float* __restrict__ out_ijk) {
    const int b = blockIdx.x;
    if (b < DATA_BLOCKS) {
        const size_t j   = (size_t)b * 256 + threadIdx.x;   // output float4 index
        const size_t src = ((j >> 7) << 4) | (j & 15);      // parent*16 + c4
        __builtin_nontemporal_store(in[src], out_data + j);
    } else {
        const int e = (b - DATA_BLOCKS) * 256 + threadIdx.x;  // [0, IJK_ELEMS)
        const int r = e / 3;           // fine row (magic-mul)
        const int d = e - r * 3;       // dim 0..2
        const int n = r >> 3;          // parent voxel
        const int o = r & 7;           // child index
        const int off = (o >> (2 - d)) & 1;  // meshgrid ij-order offset bit
        __builtin_nontemporal_store((float)(ijk[n * 3 + d] * 2 + off), out_ijk + e);
    }
}

extern "C" void kernel_launch(void* const* d_in, const int* in_sizes, int n_in,
                              void* d_out, int out_size, void* d_ws, size_t ws_size,
                              hipStream_t stream) {
    const nfloat4* coarse_data = (const nfloat4*)d_in[0];
    const int*     coarse_ijk  = (const int*)d_in[1];

    float*   out      = (float*)d_out;
    nfloat4* out_data = (nfloat4*)out;
    float*   out_ijk  = out + (size_t)N_COARSE * 8 * CHANNELS;  // +134217728

    upsample_fused_kernel<<<DATA_BLOCKS + IJK_BLOCKS, 256, 0, stream>>>(
        coarse_data, coarse_ijk, out_data, out_ijk);
}